// Round 4
// baseline (198.398 us; speedup 1.0000x reference)
//
#include <hip/hip_runtime.h>
#include <cstdint>
#include <cstddef>

// B=4, S=2048, D=1024, H=16, HD=64 ; BS=8192 rows; qkv N=3072
typedef float  f32x4  __attribute__((ext_vector_type(4)));
typedef __bf16 bf16x8 __attribute__((ext_vector_type(8)));
typedef __bf16 bf16x4 __attribute__((ext_vector_type(4)));

#define DEVI static __device__ __forceinline__

DEVI f32x4 mfma_bf16(bf16x8 a, bf16x8 b, f32x4 c) {
  return __builtin_amdgcn_mfma_f32_16x16x32_bf16(a, b, c, 0, 0, 0);
}

DEVI void gload_lds16(const void* g, void* l) {
  __builtin_amdgcn_global_load_lds(
      (const __attribute__((address_space(1))) void*)g,
      (__attribute__((address_space(3))) void*)l, 16, 0, 0);
}

// ---------------- cast f32 -> bf16, 4 elems/thread ----------------
__global__ void k_cast_bf16(const float* __restrict__ src, __bf16* __restrict__ dst, int n4) {
  int i = blockIdx.x * blockDim.x + threadIdx.x;
  if (i < n4) {
    float4 v = reinterpret_cast<const float4*>(src)[i];
    bf16x4 r;
    r.x = (__bf16)v.x; r.y = (__bf16)v.y; r.z = (__bf16)v.z; r.w = (__bf16)v.w;
    reinterpret_cast<bf16x4*>(dst)[i] = r;
  }
}

// ---------------- transpose + cast: f32 [R][C] -> bf16 [C][R] ----------------
__global__ void k_transpose_cast(const float* __restrict__ src, __bf16* __restrict__ dst,
                                 int R, int C) {
  __shared__ __bf16 tile[64][65];
  const int tx = threadIdx.x & 63, ty = threadIdx.x >> 6;
  const int r0 = blockIdx.y * 64, c0 = blockIdx.x * 64;
#pragma unroll
  for (int i = 0; i < 16; ++i) {
    int r = ty * 16 + i;
    tile[r][tx] = (__bf16)src[(size_t)(r0 + r) * C + c0 + tx];
  }
  __syncthreads();
#pragma unroll
  for (int i = 0; i < 16; ++i) {
    int c = ty * 16 + i;
    dst[(size_t)(c0 + c) * R + r0 + tx] = tile[tx][c];
  }
}

// ---------------- transpose V section of qkv -> VT [B*H][64][2048] ----------------
__global__ void k_transpose_v(const __bf16* __restrict__ qkv, __bf16* __restrict__ VT) {
  __shared__ __bf16 tile[64][65];
  const int tx = threadIdx.x & 63, ty = threadIdx.x >> 6;
  const int bh = blockIdx.y;              // 0..63
  const int b = bh >> 4, h = bh & 15;
  const int s0 = blockIdx.x * 64;
  const __bf16* src = qkv + (size_t)(b * 2048) * 3072 + 2048 + h * 64;
#pragma unroll
  for (int i = 0; i < 16; ++i) {
    int s = ty * 16 + i;
    tile[s][tx] = src[(size_t)(s0 + s) * 3072 + tx];
  }
  __syncthreads();
  __bf16* dst = VT + (size_t)bh * 64 * 2048;
#pragma unroll
  for (int i = 0; i < 16; ++i) {
    int d = ty * 16 + i;
    dst[(size_t)d * 2048 + s0 + tx] = tile[tx][d];
  }
}

// ---------------- bf16 GEMM, triple-buffered counted-vmcnt ----------------
// C[M][N] = A[M][K] * Bt[N][K]^T + bias. BM=128, BN=256, BK=64.
// 512 threads = 8 waves (wr=w&1: 64 M-rows, wc=w>>1: 64 N-cols each).
// 3 LDS buffers (48KB each); iter t: stage(t+2), compute(t), vmcnt(6), s_barrier.
// Loads span ~1 full K-tile of compute -> no drain-0 stall (T4).
template <int MODE>  // 0: bf16 out, 1: f32 out
__global__ __launch_bounds__(512, 2) void k_gemm3(
    const __bf16* __restrict__ A, const __bf16* __restrict__ Bt,
    const float* __restrict__ bias, void* __restrict__ Cv,
    int M, int N, int K, int nbx) {
  __shared__ __bf16 Ab[3][128 * 64];  // 48 KB
  __shared__ __bf16 Bb[3][256 * 64];  // 96 KB
  const int t = threadIdx.x;
  const int w = t >> 6, lane = t & 63;
  const int l15 = lane & 15, lg = lane >> 4;
  const int wr = w & 1, wc = w >> 1;

  // XCD-aware bijective swizzle (gridDim.x % 8 == 0): m-chunk per XCD.
  const int nwg = gridDim.x;
  const int wgid = (blockIdx.x & 7) * (nwg >> 3) + (blockIdx.x >> 3);
  const int m0 = (wgid / nbx) * 128;
  const int n0 = (wgid % nbx) * 256;

  // ---- staging setup: per-thread global srcs (pre-swizzled), linear LDS dest ----
  const int tid8 = t >> 3, slot = t & 7;
  const int swb = (slot ^ (tid8 & 7)) << 4;              // pre-swizzle byte
  const char* pA0 = (const char*)(A + (size_t)(m0 + tid8) * K) + swb;
  const char* pB0 = (const char*)(Bt + (size_t)(n0 + tid8) * K) + swb;
  const size_t ROWS64 = (size_t)64 * K * 2;              // 64 rows of K bf16

  auto stage = [&](int buf, int kt) {
    const size_t ko = (size_t)kt * 128;                  // 64 bf16 = 128 B along K
#pragma unroll
    for (int i = 0; i < 2; ++i)
      gload_lds16(pA0 + ko + i * ROWS64, (char*)Ab[buf] + i * 8192 + w * 1024);
#pragma unroll
    for (int i = 0; i < 4; ++i)
      gload_lds16(pB0 + ko + i * ROWS64, (char*)Bb[buf] + i * 8192 + w * 1024);
  };

  // ---- per-lane fragment read offsets (bytes, ks=0; ks=1 toggles bit 6 via XOR) ----
  int offA[4], offB[4];
#pragma unroll
  for (int m = 0; m < 4; ++m) {
    int row = wr * 64 + m * 16 + l15;
    offA[m] = row * 128 + ((lg * 16) ^ ((row & 7) << 4));
  }
#pragma unroll
  for (int n = 0; n < 4; ++n) {
    int row = wc * 64 + n * 16 + l15;
    offB[n] = row * 128 + ((lg * 16) ^ ((row & 7) << 4));
  }

  f32x4 acc[4][4] = {};
  const int nK = K >> 6;

  stage(0, 0);
  stage(1, 1);
  asm volatile("s_waitcnt vmcnt(6)" ::: "memory");  // tile 0 landed (tile 1 in flight)
  __builtin_amdgcn_s_barrier();

  for (int kt = 0; kt < nK; ++kt) {
    const int buf = kt % 3;
    const bool pf = (kt + 2) < nK;
    if (pf) stage((kt + 2) % 3, kt + 2);
    const char* ab = (const char*)Ab[buf];
    const char* bb = (const char*)Bb[buf];
#pragma unroll
    for (int ks = 0; ks < 2; ++ks) {
      const int kx = ks << 6;
      bf16x8 af[4], bfr[4];
#pragma unroll
      for (int m = 0; m < 4; ++m) af[m] = *(const bf16x8*)(ab + (offA[m] ^ kx));
#pragma unroll
      for (int n = 0; n < 4; ++n) bfr[n] = *(const bf16x8*)(bb + (offB[n] ^ kx));
      __builtin_amdgcn_s_setprio(1);
#pragma unroll
      for (int m = 0; m < 4; ++m)
#pragma unroll
        for (int n = 0; n < 4; ++n)
          acc[m][n] = mfma_bf16(af[m], bfr[n], acc[m][n]);
      __builtin_amdgcn_s_setprio(0);
    }
    if (pf) {
      asm volatile("s_waitcnt vmcnt(6)" ::: "memory");  // tile kt+1 landed
    } else {
      asm volatile("s_waitcnt vmcnt(0)" ::: "memory");  // tail: drain rest
    }
    __builtin_amdgcn_s_barrier();
  }

#pragma unroll
  for (int n = 0; n < 4; ++n) {
    const int gcol = n0 + wc * 64 + n * 16 + l15;
    const float bv = bias ? bias[gcol] : 0.0f;
#pragma unroll
    for (int m = 0; m < 4; ++m) {
      const int grow = m0 + wr * 64 + m * 16 + (lg << 2);
#pragma unroll
      for (int r = 0; r < 4; ++r) {
        float v = acc[m][n][r] + bv;
        if (MODE == 0)
          ((__bf16*)Cv)[(size_t)(grow + r) * N + gcol] = (__bf16)v;
        else
          ((float*)Cv)[(size_t)(grow + r) * N + gcol] = v;
      }
    }
  }
}

// ---------------- causal flash attention (LDS-staged, swapped-QK^T in-lane softmax) ----
// grid: 2048 blocks; qt = 31-(bid>>6) (heavy-first LPT), bh = bid&63 (per-head XCD affinity).
// 4 waves x 16 q-rows; KV tile = 64. Swapped QK^T (mfma(K,Q)) puts a full q-row's scores
// in-lane: row reduce = in-lane tree + 2 shfl_xor. exp2-domain softmax, defer-max (THR=8).
__global__ __launch_bounds__(256, 2) void k_attn(
    const __bf16* __restrict__ qkv,  // [8192][3072]
    const __bf16* __restrict__ VT,   // [B*H][64][2048]
    __bf16* __restrict__ Y) {        // [8192][1024]
  __shared__ __bf16 kbuf[2][64 * 64];  // 8 KB per buf, row=kv pos, 128B rows, XOR-swizzled
  __shared__ __bf16 vbuf[2][64 * 64];  // 8 KB per buf, row=d,      128B rows, XOR-swizzled
  __shared__ __bf16 p_lds[4][1024];    // per-wave 16x64 P tile (row=q, col=kv), XOR swizzled
  const int t = threadIdx.x, w = t >> 6, lane = t & 63;
  const int l15 = lane & 15, lg = lane >> 4;
  const int bid = blockIdx.x;
  const int qt = 31 - (bid >> 6);   // heavy tiles first
  const int bh = bid & 63;          // same head -> same XCD (round-robin dispatch)
  const int b = bh >> 4, h = bh & 15;
  const int q0 = qt * 64;
  const int nkv = qt + 1;
  const float SCL = 0.125f * 1.44269504f;  // scale * log2(e): softmax in exp2 domain

  const size_t qrow = (size_t)(b * 2048 + q0 + w * 16 + l15);
  const bf16x8 qf0 = *(const bf16x8*)(qkv + qrow * 3072 + h * 64 + lg * 8);
  const bf16x8 qf1 = *(const bf16x8*)(qkv + qrow * 3072 + h * 64 + 32 + lg * 8);

  const __bf16* kg = qkv + (size_t)(b * 2048) * 3072 + 1024 + h * 64;  // +kvpos*3072
  const __bf16* vg = VT + (size_t)bh * 64 * 2048;                      // +d*2048

  const int srow = lane >> 3, sslot = lane & 7;
  auto stage = [&](int bi, int kvi) {
#pragma unroll
    for (int i = 0; i < 2; ++i) {
      int row = i * 32 + w * 8 + srow;           // 0..63
      int sb = (sslot ^ (row & 7)) << 4;         // pre-swizzled source byte
      gload_lds16((const char*)(kg + (size_t)(kvi * 64 + row) * 3072) + sb,
                  (char*)kbuf[bi] + i * 4096 + w * 1024);
      gload_lds16((const char*)(vg + (size_t)row * 2048 + kvi * 64) + sb,
                  (char*)vbuf[bi] + i * 4096 + w * 1024);
    }
  };

  f32x4 o[4] = {};
  float mr = -1e30f, lr = 0.0f;   // running max (scaled domain) & sum for q-row w*16+l15
  __bf16* pl = &p_lds[w][0];

  stage(0, 0);
  asm volatile("s_waitcnt vmcnt(0)" ::: "memory");
  __syncthreads();

  for (int kv = 0; kv < nkv; ++kv) {
    if (kv + 1 < nkv) stage((kv + 1) & 1, kv + 1);  // prefetch next tile
    const char* kb = (const char*)kbuf[kv & 1];
    const char* vb = (const char*)vbuf[kv & 1];

    // QK^T swapped: s[nb] = K_tile * Q -> D[kv_local][q]; lane: q = l15, kv = nb*16+lg*4+r
    f32x4 s[4] = {};
    __builtin_amdgcn_s_setprio(1);
#pragma unroll
    for (int nb = 0; nb < 4; ++nb) {
      int row = nb * 16 + l15;
      int sw = (row & 7) << 4;
      bf16x8 k0 = *(const bf16x8*)(kb + row * 128 + ((lg * 16) ^ sw));
      bf16x8 k1 = *(const bf16x8*)(kb + row * 128 + ((64 + lg * 16) ^ sw));
      s[nb] = mfma_bf16(k0, qf0, s[nb]);
      s[nb] = mfma_bf16(k1, qf1, s[nb]);
    }
    __builtin_amdgcn_s_setprio(0);

    if (kv == qt) {  // diagonal tile: mask kv > q (raw domain)
      const int qg = q0 + w * 16 + l15;
#pragma unroll
      for (int nb = 0; nb < 4; ++nb)
#pragma unroll
        for (int r = 0; r < 4; ++r)
          if (kv * 64 + nb * 16 + lg * 4 + r > qg) s[nb][r] = -1e30f;
    }

    // row max: in-lane tree over 16 + xor16/32 (reduce over lg groups)
    float pm = -3e38f;
#pragma unroll
    for (int nb = 0; nb < 4; ++nb)
      pm = fmaxf(pm, fmaxf(fmaxf(s[nb][0], s[nb][1]), fmaxf(s[nb][2], s[nb][3])));
    pm = fmaxf(pm, __shfl_xor(pm, 16));
    pm = fmaxf(pm, __shfl_xor(pm, 32));
    pm *= SCL;

    if (!__all(pm <= mr + 8.0f)) {  // defer-max: rescale only when max grows
      float nm = fmaxf(mr, pm);
      float alpha = __builtin_amdgcn_exp2f(mr - nm);
      lr *= alpha;
      mr = nm;
#pragma unroll
      for (int r = 0; r < 4; ++r) {
        float aO = __shfl(alpha, lg * 4 + r);   // alpha of q-row lg*4+r
        o[0][r] *= aO; o[1][r] *= aO; o[2][r] *= aO; o[3][r] *= aO;
      }
    }

    // p = exp2(s*SCL - mr); sum in-lane + xor16/32
    float ps = 0.0f;
    bf16x4 pk[4];
#pragma unroll
    for (int nb = 0; nb < 4; ++nb) {
      f32x4 pe;
#pragma unroll
      for (int r = 0; r < 4; ++r)
        pe[r] = __builtin_amdgcn_exp2f(fmaf(s[nb][r], SCL, -mr));
      ps += (pe[0] + pe[1]) + (pe[2] + pe[3]);
      pk[nb][0] = (__bf16)pe[0]; pk[nb][1] = (__bf16)pe[1];
      pk[nb][2] = (__bf16)pe[2]; pk[nb][3] = (__bf16)pe[3];
    }
    ps += __shfl_xor(ps, 16);
    ps += __shfl_xor(ps, 32);
    lr += ps;

    // store P^T values to p_lds[q=l15][kv], 4x ds_write_b64 (8B blocks, swizzle-safe)
    {
      const int rowb = l15 * 128;
      const int sw = (l15 & 7) << 4;
#pragma unroll
      for (int nb = 0; nb < 4; ++nb) {
        int cb = (nb * 32 + lg * 8) ^ sw;
        *(bf16x4*)((char*)pl + rowb + cb) = pk[nb];
      }
    }
    asm volatile("s_waitcnt lgkmcnt(0)" ::: "memory");
    bf16x8 pf0, pf1;
    {
      const int rowb = l15 * 128;
      const int sw = (l15 & 7) << 4;
      pf0 = *(const bf16x8*)((const char*)pl + rowb + ((lg << 4) ^ sw));
      pf1 = *(const bf16x8*)((const char*)pl + rowb + ((64 + (lg << 4)) ^ sw));
    }
    __builtin_amdgcn_s_setprio(1);
#pragma unroll
    for (int nb = 0; nb < 4; ++nb) {
      int row = nb * 16 + l15;
      int sw = (row & 7) << 4;
      bf16x8 v0 = *(const bf16x8*)(vb + row * 128 + ((lg * 16) ^ sw));
      bf16x8 v1 = *(const bf16x8*)(vb + row * 128 + ((64 + lg * 16) ^ sw));
      o[nb] = mfma_bf16(pf0, v0, o[nb]);
      o[nb] = mfma_bf16(pf1, v1, o[nb]);
    }
    __builtin_amdgcn_s_setprio(0);
    asm volatile("s_waitcnt vmcnt(0)" ::: "memory");  // next tile fully staged
    __syncthreads();                                  // everyone done with cur buffers
  }

  float lO[4];
#pragma unroll
  for (int r = 0; r < 4; ++r) lO[r] = __shfl(lr, lg * 4 + r);
#pragma unroll
  for (int nb = 0; nb < 4; ++nb)
#pragma unroll
    for (int r = 0; r < 4; ++r) {
      float v = o[nb][r] / lO[r];
      size_t row = (size_t)(b * 2048 + q0 + w * 16 + lg * 4 + r);
      Y[row * 1024 + h * 64 + nb * 16 + l15] = (__bf16)v;
    }
}

extern "C" void kernel_launch(void* const* d_in, const int* in_sizes, int n_in,
                              void* d_out, int out_size, void* d_ws, size_t ws_size,
                              hipStream_t stream) {
  const float* x      = (const float*)d_in[0];
  const float* w_qkv  = (const float*)d_in[1];
  const float* b_qkv  = (const float*)d_in[2];
  const float* w_proj = (const float*)d_in[3];
  const float* b_proj = (const float*)d_in[4];
  float* out = (float*)d_out;

  char* ws = (char*)d_ws;
  const size_t MB = 1024 * 1024;
  __bf16* xb     = (__bf16*)(ws);            // 16 MiB  [8192][1024]
  __bf16* wqkvT  = (__bf16*)(ws + 16 * MB);  // 6 MiB   [3072][1024]
  __bf16* wprojT = (__bf16*)(ws + 22 * MB);  // 2 MiB   [1024][1024]
  __bf16* qkv    = (__bf16*)(ws + 24 * MB);  // 48 MiB  [8192][3072]
  __bf16* VT     = (__bf16*)(ws + 72 * MB);  // 16 MiB  [64][64][2048]
  __bf16* Y      = (__bf16*)(ws + 88 * MB);  // 16 MiB  [8192][1024]  (ends 104 MiB)

  k_cast_bf16<<<8192, 256, 0, stream>>>(x, xb, 8192 * 1024 / 4);
  k_transpose_cast<<<dim3(48, 16), 256, 0, stream>>>(w_qkv, wqkvT, 1024, 3072);
  k_transpose_cast<<<dim3(16, 16), 256, 0, stream>>>(w_proj, wprojT, 1024, 1024);
  k_gemm3<0><<<dim3(64 * 12), 512, 0, stream>>>(xb, wqkvT, b_qkv, qkv, 8192, 3072, 1024, 12);
  k_transpose_v<<<dim3(32, 64), 256, 0, stream>>>(qkv, VT);
  k_attn<<<dim3(2048), 256, 0, stream>>>(qkv, VT, Y);
  k_gemm3<1><<<dim3(64 * 4), 512, 0, stream>>>(Y, wprojT, b_proj, out, 8192, 1024, 1024, 4);
}

// Round 5
// 178.238 us; speedup vs baseline: 1.1131x; 1.1131x over previous
//
#include <hip/hip_runtime.h>
#include <cstdint>
#include <cstddef>

// B=4, S=2048, D=1024, H=16, HD=64 ; BS=8192 rows; qkv N=3072
typedef float  f32x4  __attribute__((ext_vector_type(4)));
typedef __bf16 bf16x8 __attribute__((ext_vector_type(8)));
typedef __bf16 bf16x4 __attribute__((ext_vector_type(4)));

#define DEVI static __device__ __forceinline__

DEVI f32x4 mfma_bf16(bf16x8 a, bf16x8 b, f32x4 c) {
  return __builtin_amdgcn_mfma_f32_16x16x32_bf16(a, b, c, 0, 0, 0);
}

DEVI void gload_lds16(const void* g, void* l) {
  __builtin_amdgcn_global_load_lds(
      (const __attribute__((address_space(1))) void*)g,
      (__attribute__((address_space(3))) void*)l, 16, 0, 0);
}

// ---------------- cast f32 -> bf16, 4 elems/thread ----------------
__global__ void k_cast_bf16(const float* __restrict__ src, __bf16* __restrict__ dst, int n4) {
  int i = blockIdx.x * blockDim.x + threadIdx.x;
  if (i < n4) {
    float4 v = reinterpret_cast<const float4*>(src)[i];
    bf16x4 r;
    r.x = (__bf16)v.x; r.y = (__bf16)v.y; r.z = (__bf16)v.z; r.w = (__bf16)v.w;
    reinterpret_cast<bf16x4*>(dst)[i] = r;
  }
}

// ---------------- transpose + cast: f32 [R][C] -> bf16 [C][R] ----------------
__global__ void k_transpose_cast(const float* __restrict__ src, __bf16* __restrict__ dst,
                                 int R, int C) {
  __shared__ __bf16 tile[64][65];
  const int tx = threadIdx.x & 63, ty = threadIdx.x >> 6;
  const int r0 = blockIdx.y * 64, c0 = blockIdx.x * 64;
#pragma unroll
  for (int i = 0; i < 16; ++i) {
    int r = ty * 16 + i;
    tile[r][tx] = (__bf16)src[(size_t)(r0 + r) * C + c0 + tx];
  }
  __syncthreads();
#pragma unroll
  for (int i = 0; i < 16; ++i) {
    int c = ty * 16 + i;
    dst[(size_t)(c0 + c) * R + r0 + tx] = tile[tx][c];
  }
}

// ---------------- transpose V section of qkv -> VT [B*H][64][2048] ----------------
__global__ void k_transpose_v(const __bf16* __restrict__ qkv, __bf16* __restrict__ VT) {
  __shared__ __bf16 tile[64][65];
  const int tx = threadIdx.x & 63, ty = threadIdx.x >> 6;
  const int bh = blockIdx.y;              // 0..63
  const int b = bh >> 4, h = bh & 15;
  const int s0 = blockIdx.x * 64;
  const __bf16* src = qkv + (size_t)(b * 2048) * 3072 + 2048 + h * 64;
#pragma unroll
  for (int i = 0; i < 16; ++i) {
    int s = ty * 16 + i;
    tile[s][tx] = src[(size_t)(s0 + s) * 3072 + tx];
  }
  __syncthreads();
  __bf16* dst = VT + (size_t)bh * 64 * 2048;
#pragma unroll
  for (int i = 0; i < 16; ++i) {
    int d = ty * 16 + i;
    dst[(size_t)d * 2048 + s0 + tx] = tile[tx][d];
  }
}

// ---------------- bf16 GEMM: C[M][N] = A[M][K] * Bt[N][K]^T + bias ----------------
// 128x128 tile, BK=64, 4 waves (2x2), global_load_lds staging with both-sides XOR swizzle.
// (round-3 proven version; ~900 TF class)
template <int MODE>  // 0: bf16 out, 1: f32 out
__global__ __launch_bounds__(256, 2) void k_gemm_bt(
    const __bf16* __restrict__ A, const __bf16* __restrict__ Bt,
    const float* __restrict__ bias, void* __restrict__ Cv,
    int M, int N, int K, int nbx) {
  __shared__ __bf16 As[128 * 64];
  __shared__ __bf16 Bs[128 * 64];
  const int t = threadIdx.x;
  const int w = t >> 6, lane = t & 63;
  const int l15 = lane & 15, lg = lane >> 4;
  const int m0 = (blockIdx.x / nbx) * 128;
  const int n0 = (blockIdx.x % nbx) * 128;
  const int wr = w >> 1, wc = w & 1;
  const int lrow = lane >> 3, lslot = lane & 7;

  f32x4 acc[4][4] = {};

  const int nK = K >> 6;
  for (int kt = 0; kt < nK; ++kt) {
    const __bf16* Ab = A + (size_t)m0 * K + kt * 64;
    const __bf16* Bb = Bt + (size_t)n0 * K + kt * 64;
#pragma unroll
    for (int c = 0; c < 4; ++c) {
      int seg = w * 4 + c;            // 16 segments of 1KB per tile
      int row = seg * 8 + lrow;       // 0..127
      int cb = (lslot ^ (row & 7)) << 4;  // pre-swizzled global source byte
      gload_lds16((const char*)(Ab + (size_t)row * K) + cb, (char*)As + seg * 1024);
      gload_lds16((const char*)(Bb + (size_t)row * K) + cb, (char*)Bs + seg * 1024);
    }
    __syncthreads();
#pragma unroll
    for (int ks = 0; ks < 2; ++ks) {
      bf16x8 af[4], bfr[4];
      const int cb = ks * 64 + (lg << 4);
#pragma unroll
      for (int m = 0; m < 4; ++m) {
        int row = wr * 64 + m * 16 + l15;
        af[m] = *(const bf16x8*)((const char*)As + row * 128 + (cb ^ ((row & 7) << 4)));
      }
#pragma unroll
      for (int n = 0; n < 4; ++n) {
        int row = wc * 64 + n * 16 + l15;
        bfr[n] = *(const bf16x8*)((const char*)Bs + row * 128 + (cb ^ ((row & 7) << 4)));
      }
#pragma unroll
      for (int m = 0; m < 4; ++m)
#pragma unroll
        for (int n = 0; n < 4; ++n)
          acc[m][n] = mfma_bf16(af[m], bfr[n], acc[m][n]);
    }
    __syncthreads();
  }

#pragma unroll
  for (int n = 0; n < 4; ++n) {
    const int gcol = n0 + wc * 64 + n * 16 + l15;
    const float bv = bias ? bias[gcol] : 0.0f;
#pragma unroll
    for (int m = 0; m < 4; ++m) {
      const int grow = m0 + wr * 64 + m * 16 + (lg << 2);
#pragma unroll
      for (int r = 0; r < 4; ++r) {
        float v = acc[m][n][r] + bv;
        if (MODE == 0)
          ((__bf16*)Cv)[(size_t)(grow + r) * N + gcol] = (__bf16)v;
        else
          ((float*)Cv)[(size_t)(grow + r) * N + gcol] = v;
      }
    }
  }
}

// ---------------- causal flash attention (QBLK=128, 8 waves x 16 q-rows) ----------------
// grid: 1024 blocks; qt = 15-(bid>>6) (heavy-first LPT), bh = bid&63 (per-head XCD affinity).
// KV tile = 64, double-buffered LDS staging (48KB -> 3 blocks/CU = 6 waves/SIMD).
// Swapped QK^T (mfma(K,Q)): full q-row's scores in-lane; exp2-domain softmax; defer-max.
__global__ __launch_bounds__(512, 2) void k_attn(
    const __bf16* __restrict__ qkv,  // [8192][3072]
    const __bf16* __restrict__ VT,   // [B*H][64][2048]
    __bf16* __restrict__ Y) {        // [8192][1024]
  __shared__ __bf16 kbuf[2][64 * 64];  // 8 KB per buf, row=kv pos, 128B rows, XOR-swizzled
  __shared__ __bf16 vbuf[2][64 * 64];  // 8 KB per buf, row=d,      128B rows, XOR-swizzled
  __shared__ __bf16 p_lds[8][1024];    // per-wave 16x64 P tile (row=q, col=kv), XOR swizzled
  const int t = threadIdx.x, w = t >> 6, lane = t & 63;
  const int l15 = lane & 15, lg = lane >> 4;
  const int bid = blockIdx.x;
  const int qt = 15 - (bid >> 6);   // heavy q-blocks first
  const int bh = bid & 63;          // same head -> same XCD (round-robin dispatch)
  const int b = bh >> 4, h = bh & 15;
  const int q0 = qt * 128;
  const int nkv = 2 * qt + 2;
  const float SCL = 0.125f * 1.44269504f;  // scale * log2(e): softmax in exp2 domain

  const size_t qrow = (size_t)(b * 2048 + q0 + w * 16 + l15);
  const bf16x8 qf0 = *(const bf16x8*)(qkv + qrow * 3072 + h * 64 + lg * 8);
  const bf16x8 qf1 = *(const bf16x8*)(qkv + qrow * 3072 + h * 64 + 32 + lg * 8);

  const __bf16* kg = qkv + (size_t)(b * 2048) * 3072 + 1024 + h * 64;  // +kvpos*3072
  const __bf16* vg = VT + (size_t)bh * 64 * 2048;                      // +d*2048

  // 512 threads stage 8KB K + 8KB V per tile: 1 chunk of 16B each.
  const int srow = t >> 3, sslot = t & 7;          // row 0..63, slot 0..7
  const int sb = (sslot ^ (srow & 7)) << 4;        // pre-swizzled source byte
  auto stage = [&](int bi, int kvi) {
    gload_lds16((const char*)(kg + (size_t)(kvi * 64 + srow) * 3072) + sb,
                (char*)kbuf[bi] + w * 1024);
    gload_lds16((const char*)(vg + (size_t)srow * 2048 + kvi * 64) + sb,
                (char*)vbuf[bi] + w * 1024);
  };

  f32x4 o[4] = {};
  float mr = -1e30f, lr = 0.0f;   // running max (scaled domain) & sum for q-row w*16+l15
  __bf16* pl = &p_lds[w][0];

  stage(0, 0);
  asm volatile("s_waitcnt vmcnt(0)" ::: "memory");
  __syncthreads();

  for (int kv = 0; kv < nkv; ++kv) {
    if (kv + 1 < nkv) stage((kv + 1) & 1, kv + 1);  // prefetch next tile
    const char* kb = (const char*)kbuf[kv & 1];
    const char* vb = (const char*)vbuf[kv & 1];

    // QK^T swapped: s[nb] = K_tile * Q -> D[kv_local][q]; lane: q = l15, kv = nb*16+lg*4+r
    f32x4 s[4] = {};
    __builtin_amdgcn_s_setprio(1);
#pragma unroll
    for (int nb = 0; nb < 4; ++nb) {
      int row = nb * 16 + l15;
      int sw = (row & 7) << 4;
      bf16x8 k0 = *(const bf16x8*)(kb + row * 128 + ((lg * 16) ^ sw));
      bf16x8 k1 = *(const bf16x8*)(kb + row * 128 + ((64 + lg * 16) ^ sw));
      s[nb] = mfma_bf16(k0, qf0, s[nb]);
      s[nb] = mfma_bf16(k1, qf1, s[nb]);
    }
    __builtin_amdgcn_s_setprio(0);

    // causal mask: wave-uniform guard (tile reaches past this wave's first q-row)
    if (((kv + 1) << 6) > q0 + w * 16) {
      const int qg = q0 + w * 16 + l15;
#pragma unroll
      for (int nb = 0; nb < 4; ++nb)
#pragma unroll
        for (int r = 0; r < 4; ++r)
          if (kv * 64 + nb * 16 + lg * 4 + r > qg) s[nb][r] = -1e30f;
    }

    // row max: in-lane tree over 16 + xor16/32 (reduce over lg groups)
    float pm = -3e38f;
#pragma unroll
    for (int nb = 0; nb < 4; ++nb)
      pm = fmaxf(pm, fmaxf(fmaxf(s[nb][0], s[nb][1]), fmaxf(s[nb][2], s[nb][3])));
    pm = fmaxf(pm, __shfl_xor(pm, 16));
    pm = fmaxf(pm, __shfl_xor(pm, 32));
    pm *= SCL;

    if (!__all(pm <= mr + 8.0f)) {  // defer-max: rescale only when max grows
      float nm = fmaxf(mr, pm);
      float alpha = __builtin_amdgcn_exp2f(mr - nm);
      lr *= alpha;
      mr = nm;
#pragma unroll
      for (int r = 0; r < 4; ++r) {
        float aO = __shfl(alpha, lg * 4 + r);   // alpha of q-row lg*4+r
        o[0][r] *= aO; o[1][r] *= aO; o[2][r] *= aO; o[3][r] *= aO;
      }
    }

    // p = exp2(s*SCL - mr); sum in-lane + xor16/32
    float ps = 0.0f;
    bf16x4 pk[4];
#pragma unroll
    for (int nb = 0; nb < 4; ++nb) {
      f32x4 pe;
#pragma unroll
      for (int r = 0; r < 4; ++r)
        pe[r] = __builtin_amdgcn_exp2f(fmaf(s[nb][r], SCL, -mr));
      ps += (pe[0] + pe[1]) + (pe[2] + pe[3]);
      pk[nb][0] = (__bf16)pe[0]; pk[nb][1] = (__bf16)pe[1];
      pk[nb][2] = (__bf16)pe[2]; pk[nb][3] = (__bf16)pe[3];
    }
    ps += __shfl_xor(ps, 16);
    ps += __shfl_xor(ps, 32);
    lr += ps;

    // store P^T values to p_lds[q=l15][kv], 4x ds_write_b64 (8B blocks, swizzle-safe)
    {
      const int rowb = l15 * 128;
      const int sw = (l15 & 7) << 4;
#pragma unroll
      for (int nb = 0; nb < 4; ++nb) {
        int cb = (nb * 32 + lg * 8) ^ sw;
        *(bf16x4*)((char*)pl + rowb + cb) = pk[nb];
      }
    }
    asm volatile("s_waitcnt lgkmcnt(0)" ::: "memory");
    bf16x8 pf0, pf1;
    {
      const int rowb = l15 * 128;
      const int sw = (l15 & 7) << 4;
      pf0 = *(const bf16x8*)((const char*)pl + rowb + ((lg << 4) ^ sw));
      pf1 = *(const bf16x8*)((const char*)pl + rowb + ((64 + (lg << 4)) ^ sw));
    }
    __builtin_amdgcn_s_setprio(1);
#pragma unroll
    for (int nb = 0; nb < 4; ++nb) {
      int row = nb * 16 + l15;
      int sw = (row & 7) << 4;
      bf16x8 v0 = *(const bf16x8*)(vb + row * 128 + ((lg * 16) ^ sw));
      bf16x8 v1 = *(const bf16x8*)(vb + row * 128 + ((64 + lg * 16) ^ sw));
      o[nb] = mfma_bf16(pf0, v0, o[nb]);
      o[nb] = mfma_bf16(pf1, v1, o[nb]);
    }
    __builtin_amdgcn_s_setprio(0);
    asm volatile("s_waitcnt vmcnt(0)" ::: "memory");  // next tile fully staged
    __syncthreads();                                  // everyone done with cur buffers
  }

  float lO[4];
#pragma unroll
  for (int r = 0; r < 4; ++r) lO[r] = __shfl(lr, lg * 4 + r);
#pragma unroll
  for (int nb = 0; nb < 4; ++nb)
#pragma unroll
    for (int r = 0; r < 4; ++r) {
      float v = o[nb][r] / lO[r];
      size_t row = (size_t)(b * 2048 + q0 + w * 16 + lg * 4 + r);
      Y[row * 1024 + h * 64 + nb * 16 + l15] = (__bf16)v;
    }
}

extern "C" void kernel_launch(void* const* d_in, const int* in_sizes, int n_in,
                              void* d_out, int out_size, void* d_ws, size_t ws_size,
                              hipStream_t stream) {
  const float* x      = (const float*)d_in[0];
  const float* w_qkv  = (const float*)d_in[1];
  const float* b_qkv  = (const float*)d_in[2];
  const float* w_proj = (const float*)d_in[3];
  const float* b_proj = (const float*)d_in[4];
  float* out = (float*)d_out;

  char* ws = (char*)d_ws;
  const size_t MB = 1024 * 1024;
  __bf16* xb     = (__bf16*)(ws);            // 16 MiB  [8192][1024]
  __bf16* wqkvT  = (__bf16*)(ws + 16 * MB);  // 6 MiB   [3072][1024]
  __bf16* wprojT = (__bf16*)(ws + 22 * MB);  // 2 MiB   [1024][1024]
  __bf16* qkv    = (__bf16*)(ws + 24 * MB);  // 48 MiB  [8192][3072]
  __bf16* VT     = (__bf16*)(ws + 72 * MB);  // 16 MiB  [64][64][2048]
  __bf16* Y      = (__bf16*)(ws + 88 * MB);  // 16 MiB  [8192][1024]  (ends 104 MiB)

  k_cast_bf16<<<8192, 256, 0, stream>>>(x, xb, 8192 * 1024 / 4);
  k_transpose_cast<<<dim3(48, 16), 256, 0, stream>>>(w_qkv, wqkvT, 1024, 3072);
  k_transpose_cast<<<dim3(16, 16), 256, 0, stream>>>(w_proj, wprojT, 1024, 1024);
  k_gemm_bt<0><<<dim3(64 * 24), 256, 0, stream>>>(xb, wqkvT, b_qkv, qkv, 8192, 3072, 1024, 24);
  k_transpose_v<<<dim3(32, 64), 256, 0, stream>>>(qkv, VT);
  k_attn<<<dim3(1024), 512, 0, stream>>>(qkv, VT, Y);
  k_gemm_bt<1><<<dim3(64 * 8), 256, 0, stream>>>(Y, wprojT, b_proj, out, 8192, 1024, 1024, 8);
}